// Round 21
// baseline (191.722 us; speedup 1.0000x reference)
//
#include <hip/hip_runtime.h>
#include <hip/hip_bf16.h>

// Problem constants: B=8, N=1024, T=64, C=16, OC=16, E=16384
#define BB  8
#define NN  1024
#define TT  64
#define CC  16
#define OCC 16
#define EE  16384
#define CHO 80

typedef float  f32x4  __attribute__((ext_vector_type(4)));
typedef __bf16 bf16x8 __attribute__((ext_vector_type(8)));

// fast tanh: tanh(v) = 1 - 2/(e^{2v}+1); inf-safe both ends.
static __device__ __forceinline__ float tanh_fast(float v) {
    float e = __expf(2.0f * v);
    return 1.0f - 2.0f * __builtin_amdgcn_rcpf(e + 1.0f);
}
static __device__ __forceinline__ unsigned pk_bf16(float a, float b) {
    unsigned short lo = __builtin_bit_cast(unsigned short, (__bf16)a);
    unsigned short hi = __builtin_bit_cast(unsigned short, (__bf16)b);
    return (unsigned)lo | ((unsigned)hi << 16);
}
static __device__ __forceinline__ float bflo(unsigned u) { return __uint_as_float(u << 16); }
static __device__ __forceinline__ float bfhi(unsigned u) { return __uint_as_float(u & 0xFFFF0000u); }

// accumulate 8 bf16 (one float4) into ac[base..base+7] with weight w
static __device__ __forceinline__ void acc8(float* ac, int base, float w, float4 v) {
    unsigned ux = __float_as_uint(v.x), uy = __float_as_uint(v.y);
    unsigned uz = __float_as_uint(v.z), uw = __float_as_uint(v.w);
    ac[base + 0] = fmaf(w, bflo(ux), ac[base + 0]);
    ac[base + 1] = fmaf(w, bfhi(ux), ac[base + 1]);
    ac[base + 2] = fmaf(w, bflo(uy), ac[base + 2]);
    ac[base + 3] = fmaf(w, bfhi(uy), ac[base + 3]);
    ac[base + 4] = fmaf(w, bflo(uz), ac[base + 4]);
    ac[base + 5] = fmaf(w, bfhi(uz), ac[base + 5]);
    ac[base + 6] = fmaf(w, bflo(uw), ac[base + 6]);
    ac[base + 7] = fmaf(w, bfhi(uw), ac[base + 7]);
}

// ---------------- fused prep (unchanged) ----------------

__global__ __launch_bounds__(1024) void k_prep(
    const int* __restrict__ ei, const float* __restrict__ x,
    const float* __restrict__ w2,  const float* __restrict__ b2,
    const float* __restrict__ w3,  const float* __restrict__ b3,
    const float* __restrict__ w6,  const float* __restrict__ b6,
    const float* __restrict__ w12, const float* __restrict__ b12,
    const float* __restrict__ wg,  const float* __restrict__ bg,
    const float* __restrict__ wsl,
    int* __restrict__ offg, int* __restrict__ cntg, float* __restrict__ dinvg,
    int* __restrict__ src, float* __restrict__ wE,
    float* __restrict__ wgT, float* __restrict__ bgp, float* __restrict__ bcat,
    __bf16* __restrict__ wslh, __bf16* __restrict__ wsll, __bf16* __restrict__ wtg,
    __bf16* __restrict__ xb) {
    int tid = threadIdx.x, bid = blockIdx.x;
    const float* wsrc[4] = {w2, w3, w6, w12};
    const float* bsrc[4] = {b2, b3, b6, b12};
    const int ksA[4] = {2, 3, 6, 12};
    const int plA[4] = {0, 1, 2, 6};
    if (bid >= 14) {    // x -> bf16
        int e4 = (bid - 14) * 1024 + tid;
        float4 u = ((const float4*)x)[e4];
        uint2 w;
        w.x = pk_bf16(u.x, u.y);
        w.y = pk_bf16(u.z, u.w);
        ((uint2*)xb)[e4] = w;
        return;
    }
    if (bid == 13) {
        if (tid < 256) wgT[tid] = wg[(tid & 15) * CC + (tid >> 4)];
        else if (tid < 272) bgp[tid - 256] = bg[tid - 256];
        else if (tid < 336) { int j = tid - 272; bcat[j] = bsrc[j >> 4][j & 15]; }
        for (int e = tid; e < 4096; e += 1024) {
            float v = wsl[e];
            __bf16 h = (__bf16)v;
            wslh[e] = h;
            wsll[e] = (__bf16)(v - (float)h);
        }
        return;
    }
    if (bid != 0) {    // WTg
        int e = (bid - 1) * 1024 + tid;
        int j = e / 192, kk = e - j * 192;
        int d = kk >> 4, c = kk & 15;
        int br = j >> 4, oc = j & 15;
        int k = d - 6 + plA[br];
        float v = (k >= 0 && k < ksA[br]) ? wsrc[br][oc * (CC * ksA[br]) + c * ksA[br] + k] : 0.0f;
        wtg[e] = (__bf16)v;
        return;
    }
    __shared__ int   h[NN];
    __shared__ int   sc[NN];
    __shared__ int   cur[NN];
    __shared__ float dl[NN];
    h[tid] = 0;
    __syncthreads();
    for (int e = tid; e < EE; e += 1024) atomicAdd(&h[ei[EE + e]], 1);
    __syncthreads();
    int v = h[tid];
    sc[tid] = v;
    __syncthreads();
    for (int d = 1; d < NN; d <<= 1) {
        int add = (tid >= d) ? sc[tid - d] : 0;
        __syncthreads();
        sc[tid] += add;
        __syncthreads();
    }
    int oex = sc[tid] - v;
    float dv = rsqrtf((float)v + 1.0f);
    offg[tid] = oex; cntg[tid] = v; dinvg[tid] = dv;
    cur[tid] = oex; dl[tid] = dv;
    __syncthreads();
    for (int e = tid; e < EE; e += 1024) {
        int r = ei[e], c = ei[EE + e];
        int i = atomicAdd(&cur[c], 1);
        src[i] = r;
        wE[i]  = dl[r] * dl[c];
    }
}

// ---------------- fused main (R16 structure + launch_bounds(256,8)) ----------------
// 4 nodes/block (grid 2048, XCD-local). LDS union: xs (pre-sync2) / xh,xl2 (post-sync2).
// __launch_bounds__(256,8): cap VGPR at 64 -> 8 blocks/CU -> grid resident in ONE
// generation (R20 counters: VGPR=84 gave 6 blocks/CU -> 512-block tail at 1/4
// parallelism = the ~35us mystery cost; Occupancy 29%).

__global__ __launch_bounds__(256, 8) void k_main(
    const __bf16* __restrict__ xb, const __bf16* __restrict__ wtg,
    const float* __restrict__ bcat,
    const int* __restrict__ off, const int* __restrict__ cnt,
    const int* __restrict__ src, const float* __restrict__ wE, const float* __restrict__ dinv,
    const float* __restrict__ wgT, const float* __restrict__ bgp,
    const __bf16* __restrict__ wslh, const __bf16* __restrict__ wsll,
    const float* __restrict__ bsl, float* __restrict__ out) {
    // union: [0,14592) xs: node*3648B, 76 rows * 24 elems
    //        [0,18432) xh/xl2: node*4608B (+2304 for lo), 16*72 elems each
    __shared__ __align__(16) char smem[18432];
    int tid = threadIdx.x;
    int wave = tid >> 6, lane = tid & 63;
    int l15 = lane & 15, g = lane >> 4;
    int bq = blockIdx.x & 7, nq = blockIdx.x >> 3;
    int n = nq * 4 + wave;
    const __bf16* xbb = xb + (size_t)bq * NN * (TT * CC);

    // tconv A-frags (weights, oc-rows wave*16+l15) + bias
    bf16x8 afr[6];
#pragma unroll
    for (int s = 0; s < 6; s++) {
        const __bf16* p = wtg + (wave * 16 + l15) * 192 + s * 32 + g * 8;
        afr[s] = __builtin_bit_cast(bf16x8, *(const float4*)p);
    }
    float4 bias = *(const float4*)(bcat + wave * 16 + g * 4);

    {   // stage 4 node tiles into xs
        int t = tid >> 2, c0 = (tid & 3) * 4;
#pragma unroll
        for (int node = 0; node < 4; node++) {
            __bf16* xsn = (__bf16*)(smem + node * 3648);
            uint2 w = *(const uint2*)(xbb + (size_t)(nq * 4 + node) * (TT * CC) + tid * 4);
            *(uint2*)(xsn + (t + 6) * 24 + c0) = w;
            if (t == 0) {
#pragma unroll
                for (int r = 0; r < 6; r++) *(uint2*)(xsn + r * 24 + c0) = w;
            }
            if (t == 63) {
#pragma unroll
                for (int r = 70; r < 76; r++) *(uint2*)(xsn + r * 24 + c0) = w;
            }
        }
    }
    __syncthreads();

    // ---- tconv: wave = oc-block over all 4 nodes (reads xs), float4 stores ----
    for (int node = 0; node < 4; node++) {
        const __bf16* xsn = (const __bf16*)(smem + node * 3648);
        size_t bn = (size_t)bq * NN + nq * 4 + node;
        f32x4 acc[4];
#pragma unroll
        for (int m = 0; m < 4; m++) acc[m] = (f32x4){bias.x, bias.y, bias.z, bias.w};
#pragma unroll
        for (int m = 0; m < 4; m++) {
#pragma unroll
            for (int s = 0; s < 6; s++) {
                const __bf16* p = xsn + (m * 16 + l15 + 2 * s + (g >> 1)) * 24 + (g & 1) * 8;
                bf16x8 b = __builtin_bit_cast(bf16x8, *(const float4*)p);
                acc[m] = __builtin_amdgcn_mfma_f32_16x16x32_bf16(afr[s], b, acc[m], 0, 0, 0);
            }
        }
#pragma unroll
        for (int m = 0; m < 4; m++) {
            float4 o;
            o.x = tanh_fast(acc[m][0]); o.y = tanh_fast(acc[m][1]);
            o.z = tanh_fast(acc[m][2]); o.w = tanh_fast(acc[m][3]);
            *(float4*)(out + (bn * TT + m * 16 + l15) * CHO + wave * 16 + g * 4) = o;
        }
    }

    // ---- gather (wave = node, lane = t), unroll-4: 8 tile loads in flight ----
    float ac[16];
    {
        int o0 = off[n], cn_ = cnt[n];
        float d = dinv[n], d2 = d * d;
        const __bf16* st = xbb + (size_t)n * (TT * CC) + lane * 16;
        float4 s0 = *(const float4*)st;
        float4 s1 = *(const float4*)(st + 8);
        {
            unsigned ux = __float_as_uint(s0.x), uy = __float_as_uint(s0.y);
            unsigned uz = __float_as_uint(s0.z), uw = __float_as_uint(s0.w);
            ac[0] = d2 * bflo(ux); ac[1] = d2 * bfhi(ux);
            ac[2] = d2 * bflo(uy); ac[3] = d2 * bfhi(uy);
            ac[4] = d2 * bflo(uz); ac[5] = d2 * bfhi(uz);
            ac[6] = d2 * bflo(uw); ac[7] = d2 * bfhi(uw);
            ux = __float_as_uint(s1.x); uy = __float_as_uint(s1.y);
            uz = __float_as_uint(s1.z); uw = __float_as_uint(s1.w);
            ac[8]  = d2 * bflo(ux); ac[9]  = d2 * bfhi(ux);
            ac[10] = d2 * bflo(uy); ac[11] = d2 * bfhi(uy);
            ac[12] = d2 * bflo(uz); ac[13] = d2 * bfhi(uz);
            ac[14] = d2 * bflo(uw); ac[15] = d2 * bfhi(uw);
        }
        const int* srcp = src + o0;
        const float* wEp = wE + o0;
        int j = 0;
        for (; j + 4 <= cn_; j += 4) {
            int sA = srcp[j], sB = srcp[j + 1], sC = srcp[j + 2], sD = srcp[j + 3];
            float wA = wEp[j], wB = wEp[j + 1], wC = wEp[j + 2], wD = wEp[j + 3];
            const __bf16* pa = xbb + (size_t)sA * (TT * CC) + lane * 16;
            const __bf16* pb = xbb + (size_t)sB * (TT * CC) + lane * 16;
            const __bf16* pc = xbb + (size_t)sC * (TT * CC) + lane * 16;
            const __bf16* pd = xbb + (size_t)sD * (TT * CC) + lane * 16;
            float4 a0 = *(const float4*)pa, a1 = *(const float4*)(pa + 8);
            float4 b0 = *(const float4*)pb, b1 = *(const float4*)(pb + 8);
            float4 c0 = *(const float4*)pc, c1 = *(const float4*)(pc + 8);
            float4 d0 = *(const float4*)pd, d1 = *(const float4*)(pd + 8);
            acc8(ac, 0, wA, a0); acc8(ac, 8, wA, a1);
            acc8(ac, 0, wB, b0); acc8(ac, 8, wB, b1);
            acc8(ac, 0, wC, c0); acc8(ac, 8, wC, c1);
            acc8(ac, 0, wD, d0); acc8(ac, 8, wD, d1);
        }
        for (; j < cn_; j++) {
            int sA = srcp[j];
            float wA = wEp[j];
            const __bf16* pa = xbb + (size_t)sA * (TT * CC) + lane * 16;
            float4 a0 = *(const float4*)pa, a1 = *(const float4*)(pa + 8);
            acc8(ac, 0, wA, a0); acc8(ac, 8, wA, a1);
        }
    }

    // ---- transform in registers: pv[16] (kept live across sync2) ----
    float pv[16];
#pragma unroll
    for (int o = 0; o < 16; o++) {
        float p = bgp[o];
#pragma unroll
        for (int c = 0; c < 16; c++) p = fmaf(wgT[c * 16 + o], ac[c], p);
        pv[o] = p;
    }
    __syncthreads();   // all xs reads done -> safe to overwrite union with xh/xl2

    {   // write hi/lo xlA^T for wave's node
        __bf16* xhn = (__bf16*)(smem + wave * 4608);
        __bf16* xln = (__bf16*)(smem + wave * 4608 + 2304);
#pragma unroll
        for (int o = 0; o < 16; o++) {
            __bf16 h = (__bf16)pv[o];
            xhn[o * 72 + lane] = h;
            xln[o * 72 + lane] = (__bf16)(pv[o] - (float)h);
        }
    }
    __syncthreads();

    // ---- slin MFMA: wave = s-quadrant, loop 4 nodes ----
    int sglob = wave * 16 + l15;
    bf16x8 bh[2], bl[2];
#pragma unroll
    for (int k = 0; k < 2; k++) {
        bh[k] = __builtin_bit_cast(bf16x8, *(const float4*)(wslh + sglob * 64 + k * 32 + g * 8));
        bl[k] = __builtin_bit_cast(bf16x8, *(const float4*)(wsll + sglob * 64 + k * 32 + g * 8));
    }
    float bv = bsl[sglob];
    for (int node = 0; node < 4; node++) {
        const __bf16* xhn = (const __bf16*)(smem + node * 4608);
        const __bf16* xln = (const __bf16*)(smem + node * 4608 + 2304);
        f32x4 acc = (f32x4){bv, bv, bv, bv};
        bf16x8 ah[2], al[2];
#pragma unroll
        for (int k = 0; k < 2; k++) {
            ah[k] = __builtin_bit_cast(bf16x8, *(const float4*)(xhn + l15 * 72 + k * 32 + g * 8));
            al[k] = __builtin_bit_cast(bf16x8, *(const float4*)(xln + l15 * 72 + k * 32 + g * 8));
        }
#pragma unroll
        for (int k = 0; k < 2; k++) {
            acc = __builtin_amdgcn_mfma_f32_16x16x32_bf16(ah[k], bh[k], acc, 0, 0, 0);
            acc = __builtin_amdgcn_mfma_f32_16x16x32_bf16(al[k], bh[k], acc, 0, 0, 0);
            acc = __builtin_amdgcn_mfma_f32_16x16x32_bf16(ah[k], bl[k], acc, 0, 0, 0);
        }
        float4 o4;
        o4.x = tanh_fast(acc[0]); o4.y = tanh_fast(acc[1]);
        o4.z = tanh_fast(acc[2]); o4.w = tanh_fast(acc[3]);
        size_t bn = (size_t)bq * NN + nq * 4 + node;
        *(float4*)(out + (bn * TT + sglob) * CHO + 64 + g * 4) = o4;
    }
}

// ---------------- launch ----------------

extern "C" void kernel_launch(void* const* d_in, const int* in_sizes, int n_in,
                              void* d_out, int out_size, void* d_ws, size_t ws_size,
                              hipStream_t stream) {
    const float* x   = (const float*)d_in[0];
    const int*   ei  = (const int*)d_in[1];
    const float* w2  = (const float*)d_in[2];
    const float* b2  = (const float*)d_in[3];
    const float* w3  = (const float*)d_in[4];
    const float* b3  = (const float*)d_in[5];
    const float* w6  = (const float*)d_in[6];
    const float* b6  = (const float*)d_in[7];
    const float* w12 = (const float*)d_in[8];
    const float* b12 = (const float*)d_in[9];
    const float* wg  = (const float*)d_in[10];
    const float* bg  = (const float*)d_in[11];
    const float* wsl = (const float*)d_in[12];
    const float* bsl = (const float*)d_in[13];
    float* out = (float*)d_out;

    // ws layout (bytes): off|cnt|dinv|src|wE|wgT|bgp|bcat|wslh|wsll|wtg ... xb @4MB
    char*   ws   = (char*)d_ws;
    int*    off  = (int*)(ws);
    int*    cnt  = (int*)(ws + 4096);
    float*  dinv = (float*)(ws + 8192);
    int*    src  = (int*)(ws + 12288);
    float*  wE   = (float*)(ws + 77824);
    float*  wgT  = (float*)(ws + 143360);
    float*  bgp  = (float*)(ws + 144384);
    float*  bcat = (float*)(ws + 144448);
    __bf16* wslh = (__bf16*)(ws + 144704);
    __bf16* wsll = (__bf16*)(ws + 152896);
    __bf16* wtg  = (__bf16*)(ws + 161088);
    __bf16* xb   = (__bf16*)(ws + 4194304);

    k_prep<<<2062, 1024, 0, stream>>>(ei, x, w2, b2, w3, b3, w6, b6, w12, b12, wg, bg, wsl,
                                      off, cnt, dinv, src, wE, wgT, bgp, bcat,
                                      wslh, wsll, wtg, xb);
    k_main<<<BB * NN / 4, 256, 0, stream>>>(xb, wtg, bcat, off, cnt, src, wE, dinv,
                                            wgT, bgp, wslh, wsll, bsl, out);
}

// Round 22
// 121.982 us; speedup vs baseline: 1.5717x; 1.5717x over previous
//
#include <hip/hip_runtime.h>
#include <hip/hip_bf16.h>

// Problem constants: B=8, N=1024, T=64, C=16, OC=16, E=16384
#define BB  8
#define NN  1024
#define TT  64
#define CC  16
#define OCC 16
#define EE  16384
#define CHO 80
#define NQUAD 2048   // 8192 nodes / 4 per quad

typedef float  f32x4  __attribute__((ext_vector_type(4)));
typedef __bf16 bf16x8 __attribute__((ext_vector_type(8)));

// fast tanh: tanh(v) = 1 - 2/(e^{2v}+1); inf-safe both ends.
static __device__ __forceinline__ float tanh_fast(float v) {
    float e = __expf(2.0f * v);
    return 1.0f - 2.0f * __builtin_amdgcn_rcpf(e + 1.0f);
}
static __device__ __forceinline__ unsigned pk_bf16(float a, float b) {
    unsigned short lo = __builtin_bit_cast(unsigned short, (__bf16)a);
    unsigned short hi = __builtin_bit_cast(unsigned short, (__bf16)b);
    return (unsigned)lo | ((unsigned)hi << 16);
}
static __device__ __forceinline__ float bflo(unsigned u) { return __uint_as_float(u << 16); }
static __device__ __forceinline__ float bfhi(unsigned u) { return __uint_as_float(u & 0xFFFF0000u); }

// accumulate 8 bf16 (one float4) into ac[base..base+7] with weight w
static __device__ __forceinline__ void acc8(float* ac, int base, float w, float4 v) {
    unsigned ux = __float_as_uint(v.x), uy = __float_as_uint(v.y);
    unsigned uz = __float_as_uint(v.z), uw = __float_as_uint(v.w);
    ac[base + 0] = fmaf(w, bflo(ux), ac[base + 0]);
    ac[base + 1] = fmaf(w, bfhi(ux), ac[base + 1]);
    ac[base + 2] = fmaf(w, bflo(uy), ac[base + 2]);
    ac[base + 3] = fmaf(w, bfhi(uy), ac[base + 3]);
    ac[base + 4] = fmaf(w, bflo(uz), ac[base + 4]);
    ac[base + 5] = fmaf(w, bfhi(uz), ac[base + 5]);
    ac[base + 6] = fmaf(w, bflo(uw), ac[base + 6]);
    ac[base + 7] = fmaf(w, bfhi(uw), ac[base + 7]);
}

// ---------------- fused prep ----------------

__global__ __launch_bounds__(1024) void k_prep(
    const int* __restrict__ ei, const float* __restrict__ x,
    const float* __restrict__ w2,  const float* __restrict__ b2,
    const float* __restrict__ w3,  const float* __restrict__ b3,
    const float* __restrict__ w6,  const float* __restrict__ b6,
    const float* __restrict__ w12, const float* __restrict__ b12,
    const float* __restrict__ wg,  const float* __restrict__ bg,
    const float* __restrict__ wsl,
    int* __restrict__ offg, int* __restrict__ cntg, float* __restrict__ dinvg,
    int* __restrict__ src, float* __restrict__ wE,
    float* __restrict__ wgT, float* __restrict__ bgp, float* __restrict__ bcat,
    __bf16* __restrict__ wslh, __bf16* __restrict__ wsll, __bf16* __restrict__ wtg,
    __bf16* __restrict__ xb, int* __restrict__ qctr) {
    int tid = threadIdx.x, bid = blockIdx.x;
    const float* wsrc[4] = {w2, w3, w6, w12};
    const float* bsrc[4] = {b2, b3, b6, b12};
    const int ksA[4] = {2, 3, 6, 12};
    const int plA[4] = {0, 1, 2, 6};
    if (bid >= 14) {    // x -> bf16
        int e4 = (bid - 14) * 1024 + tid;
        float4 u = ((const float4*)x)[e4];
        uint2 w;
        w.x = pk_bf16(u.x, u.y);
        w.y = pk_bf16(u.z, u.w);
        ((uint2*)xb)[e4] = w;
        return;
    }
    if (bid == 13) {
        if (tid < 256) wgT[tid] = wg[(tid & 15) * CC + (tid >> 4)];
        else if (tid < 272) bgp[tid - 256] = bg[tid - 256];
        else if (tid < 336) { int j = tid - 272; bcat[j] = bsrc[j >> 4][j & 15]; }
        else if (tid == 400) qctr[0] = 0;             // reset work queue every launch
        for (int e = tid; e < 4096; e += 1024) {
            float v = wsl[e];
            __bf16 h = (__bf16)v;
            wslh[e] = h;
            wsll[e] = (__bf16)(v - (float)h);
        }
        return;
    }
    if (bid != 0) {    // WTg
        int e = (bid - 1) * 1024 + tid;
        int j = e / 192, kk = e - j * 192;
        int d = kk >> 4, c = kk & 15;
        int br = j >> 4, oc = j & 15;
        int k = d - 6 + plA[br];
        float v = (k >= 0 && k < ksA[br]) ? wsrc[br][oc * (CC * ksA[br]) + c * ksA[br] + k] : 0.0f;
        wtg[e] = (__bf16)v;
        return;
    }
    __shared__ int   h[NN];
    __shared__ int   sc[NN];
    __shared__ int   cur[NN];
    __shared__ float dl[NN];
    h[tid] = 0;
    __syncthreads();
    for (int e = tid; e < EE; e += 1024) atomicAdd(&h[ei[EE + e]], 1);
    __syncthreads();
    int v = h[tid];
    sc[tid] = v;
    __syncthreads();
    for (int d = 1; d < NN; d <<= 1) {
        int add = (tid >= d) ? sc[tid - d] : 0;
        __syncthreads();
        sc[tid] += add;
        __syncthreads();
    }
    int oex = sc[tid] - v;
    float dv = rsqrtf((float)v + 1.0f);
    offg[tid] = oex; cntg[tid] = v; dinvg[tid] = dv;
    cur[tid] = oex; dl[tid] = dv;
    __syncthreads();
    for (int e = tid; e < EE; e += 1024) {
        int r = ei[e], c = ei[EE + e];
        int i = atomicAdd(&cur[c], 1);
        src[i] = r;
        wE[i]  = dl[r] * dl[c];
    }
}

// ---------------- work-stealing fused main (R16 body per quad) ----------------
// Persistent-ish: grid 2048, each block pulls quads from an atomic queue until empty.
// Removes the convoy tail (R20: static capacity 6 blocks/CU vs grid 8/CU -> 512-block
// tail at 2/CU = the ~35us cost; R21 proved occupancy responds but VGPR-forcing spills).
// Queue order: batch = quad>>8 -> one 2.1MB batch slice hot chip-wide at a time.

__global__ __launch_bounds__(256) void k_main(
    const __bf16* __restrict__ xb, const __bf16* __restrict__ wtg,
    const float* __restrict__ bcat,
    const int* __restrict__ off, const int* __restrict__ cnt,
    const int* __restrict__ src, const float* __restrict__ wE, const float* __restrict__ dinv,
    const float* __restrict__ wgT, const float* __restrict__ bgp,
    const __bf16* __restrict__ wslh, const __bf16* __restrict__ wsll,
    const float* __restrict__ bsl, float* __restrict__ out, int* __restrict__ qctr) {
    // union: [0,14592) xs: node*3648B; [0,18432) xh/xl2: node*4608B (+2304 lo)
    __shared__ __align__(16) char smem[18432];
    __shared__ int s_quad;
    int tid = threadIdx.x;
    int wave = tid >> 6, lane = tid & 63;
    int l15 = lane & 15, g = lane >> 4;

    // quad-independent state (hoisted): tconv weights + bias for this wave's oc-block
    bf16x8 afr[6];
#pragma unroll
    for (int s = 0; s < 6; s++) {
        const __bf16* p = wtg + (wave * 16 + l15) * 192 + s * 32 + g * 8;
        afr[s] = __builtin_bit_cast(bf16x8, *(const float4*)p);
    }
    float4 bias = *(const float4*)(bcat + wave * 16 + g * 4);

    while (true) {
        if (tid == 0) s_quad = atomicAdd(qctr, 1);
        __syncthreads();
        int quad = s_quad;
        if (quad >= NQUAD) return;
        int bq = quad >> 8, nq = quad & 255;     // sequential batches -> hot L2 window
        int n = nq * 4 + wave;
        const __bf16* xbb = xb + (size_t)bq * NN * (TT * CC);

        {   // stage 4 node tiles into xs
            int t = tid >> 2, c0 = (tid & 3) * 4;
#pragma unroll
            for (int node = 0; node < 4; node++) {
                __bf16* xsn = (__bf16*)(smem + node * 3648);
                uint2 w = *(const uint2*)(xbb + (size_t)(nq * 4 + node) * (TT * CC) + tid * 4);
                *(uint2*)(xsn + (t + 6) * 24 + c0) = w;
                if (t == 0) {
#pragma unroll
                    for (int r = 0; r < 6; r++) *(uint2*)(xsn + r * 24 + c0) = w;
                }
                if (t == 63) {
#pragma unroll
                    for (int r = 70; r < 76; r++) *(uint2*)(xsn + r * 24 + c0) = w;
                }
            }
        }
        __syncthreads();

        // ---- tconv: wave = oc-block over all 4 nodes (reads xs), float4 stores ----
        for (int node = 0; node < 4; node++) {
            const __bf16* xsn = (const __bf16*)(smem + node * 3648);
            size_t bn = (size_t)bq * NN + nq * 4 + node;
            f32x4 acc[4];
#pragma unroll
            for (int m = 0; m < 4; m++) acc[m] = (f32x4){bias.x, bias.y, bias.z, bias.w};
#pragma unroll
            for (int m = 0; m < 4; m++) {
#pragma unroll
                for (int s = 0; s < 6; s++) {
                    const __bf16* p = xsn + (m * 16 + l15 + 2 * s + (g >> 1)) * 24 + (g & 1) * 8;
                    bf16x8 b = __builtin_bit_cast(bf16x8, *(const float4*)p);
                    acc[m] = __builtin_amdgcn_mfma_f32_16x16x32_bf16(afr[s], b, acc[m], 0, 0, 0);
                }
            }
#pragma unroll
            for (int m = 0; m < 4; m++) {
                float4 o;
                o.x = tanh_fast(acc[m][0]); o.y = tanh_fast(acc[m][1]);
                o.z = tanh_fast(acc[m][2]); o.w = tanh_fast(acc[m][3]);
                *(float4*)(out + (bn * TT + m * 16 + l15) * CHO + wave * 16 + g * 4) = o;
            }
        }

        // ---- gather (wave = node, lane = t), unroll-4 ----
        float ac[16];
        {
            int o0 = off[n], cn_ = cnt[n];
            float d = dinv[n], d2 = d * d;
            const __bf16* st = xbb + (size_t)n * (TT * CC) + lane * 16;
            float4 s0 = *(const float4*)st;
            float4 s1 = *(const float4*)(st + 8);
            {
                unsigned ux = __float_as_uint(s0.x), uy = __float_as_uint(s0.y);
                unsigned uz = __float_as_uint(s0.z), uw = __float_as_uint(s0.w);
                ac[0] = d2 * bflo(ux); ac[1] = d2 * bfhi(ux);
                ac[2] = d2 * bflo(uy); ac[3] = d2 * bfhi(uy);
                ac[4] = d2 * bflo(uz); ac[5] = d2 * bfhi(uz);
                ac[6] = d2 * bflo(uw); ac[7] = d2 * bfhi(uw);
                ux = __float_as_uint(s1.x); uy = __float_as_uint(s1.y);
                uz = __float_as_uint(s1.z); uw = __float_as_uint(s1.w);
                ac[8]  = d2 * bflo(ux); ac[9]  = d2 * bfhi(ux);
                ac[10] = d2 * bflo(uy); ac[11] = d2 * bfhi(uy);
                ac[12] = d2 * bflo(uz); ac[13] = d2 * bfhi(uz);
                ac[14] = d2 * bflo(uw); ac[15] = d2 * bfhi(uw);
            }
            const int* srcp = src + o0;
            const float* wEp = wE + o0;
            int j = 0;
            for (; j + 4 <= cn_; j += 4) {
                int sA = srcp[j], sB = srcp[j + 1], sC = srcp[j + 2], sD = srcp[j + 3];
                float wA = wEp[j], wB = wEp[j + 1], wC = wEp[j + 2], wD = wEp[j + 3];
                const __bf16* pa = xbb + (size_t)sA * (TT * CC) + lane * 16;
                const __bf16* pb = xbb + (size_t)sB * (TT * CC) + lane * 16;
                const __bf16* pc = xbb + (size_t)sC * (TT * CC) + lane * 16;
                const __bf16* pd = xbb + (size_t)sD * (TT * CC) + lane * 16;
                float4 a0 = *(const float4*)pa, a1 = *(const float4*)(pa + 8);
                float4 b0 = *(const float4*)pb, b1 = *(const float4*)(pb + 8);
                float4 c0 = *(const float4*)pc, c1 = *(const float4*)(pc + 8);
                float4 d0 = *(const float4*)pd, d1 = *(const float4*)(pd + 8);
                acc8(ac, 0, wA, a0); acc8(ac, 8, wA, a1);
                acc8(ac, 0, wB, b0); acc8(ac, 8, wB, b1);
                acc8(ac, 0, wC, c0); acc8(ac, 8, wC, c1);
                acc8(ac, 0, wD, d0); acc8(ac, 8, wD, d1);
            }
            for (; j < cn_; j++) {
                int sA = srcp[j];
                float wA = wEp[j];
                const __bf16* pa = xbb + (size_t)sA * (TT * CC) + lane * 16;
                float4 a0 = *(const float4*)pa, a1 = *(const float4*)(pa + 8);
                acc8(ac, 0, wA, a0); acc8(ac, 8, wA, a1);
            }
        }

        // ---- transform in registers ----
        float pv[16];
#pragma unroll
        for (int o = 0; o < 16; o++) {
            float p = bgp[o];
#pragma unroll
            for (int c = 0; c < 16; c++) p = fmaf(wgT[c * 16 + o], ac[c], p);
            pv[o] = p;
        }
        __syncthreads();   // xs reads done -> safe to overwrite union with xh/xl2

        {   // write hi/lo xlA^T for wave's node
            __bf16* xhn = (__bf16*)(smem + wave * 4608);
            __bf16* xln = (__bf16*)(smem + wave * 4608 + 2304);
#pragma unroll
            for (int o = 0; o < 16; o++) {
                __bf16 h = (__bf16)pv[o];
                xhn[o * 72 + lane] = h;
                xln[o * 72 + lane] = (__bf16)(pv[o] - (float)h);
            }
        }
        __syncthreads();

        // ---- slin MFMA: wave = s-quadrant, loop 4 nodes ----
        int sglob = wave * 16 + l15;
        bf16x8 bh[2], bl[2];
#pragma unroll
        for (int k = 0; k < 2; k++) {
            bh[k] = __builtin_bit_cast(bf16x8, *(const float4*)(wslh + sglob * 64 + k * 32 + g * 8));
            bl[k] = __builtin_bit_cast(bf16x8, *(const float4*)(wsll + sglob * 64 + k * 32 + g * 8));
        }
        float bv = bsl[sglob];
        for (int node = 0; node < 4; node++) {
            const __bf16* xhn = (const __bf16*)(smem + node * 4608);
            const __bf16* xln = (const __bf16*)(smem + node * 4608 + 2304);
            f32x4 acc = (f32x4){bv, bv, bv, bv};
            bf16x8 ah[2], al[2];
#pragma unroll
            for (int k = 0; k < 2; k++) {
                ah[k] = __builtin_bit_cast(bf16x8, *(const float4*)(xhn + l15 * 72 + k * 32 + g * 8));
                al[k] = __builtin_bit_cast(bf16x8, *(const float4*)(xln + l15 * 72 + k * 32 + g * 8));
            }
#pragma unroll
            for (int k = 0; k < 2; k++) {
                acc = __builtin_amdgcn_mfma_f32_16x16x32_bf16(ah[k], bh[k], acc, 0, 0, 0);
                acc = __builtin_amdgcn_mfma_f32_16x16x32_bf16(al[k], bh[k], acc, 0, 0, 0);
                acc = __builtin_amdgcn_mfma_f32_16x16x32_bf16(ah[k], bl[k], acc, 0, 0, 0);
            }
            float4 o4;
            o4.x = tanh_fast(acc[0]); o4.y = tanh_fast(acc[1]);
            o4.z = tanh_fast(acc[2]); o4.w = tanh_fast(acc[3]);
            size_t bn = (size_t)bq * NN + nq * 4 + node;
            *(float4*)(out + (bn * TT + sglob) * CHO + 64 + g * 4) = o4;
        }
        __syncthreads();   // smem + s_quad safe to reuse next iteration
    }
}

// ---------------- launch ----------------

extern "C" void kernel_launch(void* const* d_in, const int* in_sizes, int n_in,
                              void* d_out, int out_size, void* d_ws, size_t ws_size,
                              hipStream_t stream) {
    const float* x   = (const float*)d_in[0];
    const int*   ei  = (const int*)d_in[1];
    const float* w2  = (const float*)d_in[2];
    const float* b2  = (const float*)d_in[3];
    const float* w3  = (const float*)d_in[4];
    const float* b3  = (const float*)d_in[5];
    const float* w6  = (const float*)d_in[6];
    const float* b6  = (const float*)d_in[7];
    const float* w12 = (const float*)d_in[8];
    const float* b12 = (const float*)d_in[9];
    const float* wg  = (const float*)d_in[10];
    const float* bg  = (const float*)d_in[11];
    const float* wsl = (const float*)d_in[12];
    const float* bsl = (const float*)d_in[13];
    float* out = (float*)d_out;

    // ws layout (bytes): off|cnt|dinv|src|wE|wgT|bgp|bcat|wslh|wsll|wtg|qctr ... xb @4MB
    char*   ws   = (char*)d_ws;
    int*    off  = (int*)(ws);
    int*    cnt  = (int*)(ws + 4096);
    float*  dinv = (float*)(ws + 8192);
    int*    src  = (int*)(ws + 12288);
    float*  wE   = (float*)(ws + 77824);
    float*  wgT  = (float*)(ws + 143360);
    float*  bgp  = (float*)(ws + 144384);
    float*  bcat = (float*)(ws + 144448);
    __bf16* wslh = (__bf16*)(ws + 144704);
    __bf16* wsll = (__bf16*)(ws + 152896);
    __bf16* wtg  = (__bf16*)(ws + 161088);
    int*    qctr = (int*)(ws + 186368);
    __bf16* xb   = (__bf16*)(ws + 4194304);

    k_prep<<<2062, 1024, 0, stream>>>(ei, x, w2, b2, w3, b3, w6, b6, w12, b12, wg, bg, wsl,
                                      off, cnt, dinv, src, wE, wgT, bgp, bcat,
                                      wslh, wsll, wtg, xb, qctr);
    k_main<<<NQUAD, 256, 0, stream>>>(xb, wtg, bcat, off, cnt, src, wE, dinv,
                                      wgT, bgp, wslh, wsll, bsl, out, qctr);
}

// Round 23
// 94.367 us; speedup vs baseline: 2.0317x; 1.2926x over previous
//
#include <hip/hip_runtime.h>
#include <hip/hip_bf16.h>

// Problem constants: B=8, N=1024, T=64, C=16, OC=16, E=16384
#define BB  8
#define NN  1024
#define TT  64
#define CC  16
#define OCC 16
#define EE  16384
#define CHO 80

typedef float  f32x4  __attribute__((ext_vector_type(4)));
typedef __bf16 bf16x8 __attribute__((ext_vector_type(8)));

// fast tanh: tanh(v) = 1 - 2/(e^{2v}+1); inf-safe both ends.
static __device__ __forceinline__ float tanh_fast(float v) {
    float e = __expf(2.0f * v);
    return 1.0f - 2.0f * __builtin_amdgcn_rcpf(e + 1.0f);
}
static __device__ __forceinline__ unsigned pk_bf16(float a, float b) {
    unsigned short lo = __builtin_bit_cast(unsigned short, (__bf16)a);
    unsigned short hi = __builtin_bit_cast(unsigned short, (__bf16)b);
    return (unsigned)lo | ((unsigned)hi << 16);
}
static __device__ __forceinline__ float bflo(unsigned u) { return __uint_as_float(u << 16); }
static __device__ __forceinline__ float bfhi(unsigned u) { return __uint_as_float(u & 0xFFFF0000u); }

// accumulate 8 bf16 (one float4) into ac[base..base+7] with weight w
static __device__ __forceinline__ void acc8(float* ac, int base, float w, float4 v) {
    unsigned ux = __float_as_uint(v.x), uy = __float_as_uint(v.y);
    unsigned uz = __float_as_uint(v.z), uw = __float_as_uint(v.w);
    ac[base + 0] = fmaf(w, bflo(ux), ac[base + 0]);
    ac[base + 1] = fmaf(w, bfhi(ux), ac[base + 1]);
    ac[base + 2] = fmaf(w, bflo(uy), ac[base + 2]);
    ac[base + 3] = fmaf(w, bfhi(uy), ac[base + 3]);
    ac[base + 4] = fmaf(w, bflo(uz), ac[base + 4]);
    ac[base + 5] = fmaf(w, bfhi(uz), ac[base + 5]);
    ac[base + 6] = fmaf(w, bflo(uw), ac[base + 6]);
    ac[base + 7] = fmaf(w, bfhi(uw), ac[base + 7]);
}

// ---------------- fused prep ----------------

__global__ __launch_bounds__(1024) void k_prep(
    const int* __restrict__ ei, const float* __restrict__ x,
    const float* __restrict__ w2,  const float* __restrict__ b2,
    const float* __restrict__ w3,  const float* __restrict__ b3,
    const float* __restrict__ w6,  const float* __restrict__ b6,
    const float* __restrict__ w12, const float* __restrict__ b12,
    const float* __restrict__ wg,  const float* __restrict__ bg,
    const float* __restrict__ wsl,
    int* __restrict__ offg, int* __restrict__ cntg, float* __restrict__ dinvg,
    int* __restrict__ src, float* __restrict__ wE,
    float* __restrict__ wgT, float* __restrict__ bgp, float* __restrict__ bcat,
    __bf16* __restrict__ wslh, __bf16* __restrict__ wsll, __bf16* __restrict__ wtg,
    __bf16* __restrict__ xb) {
    int tid = threadIdx.x, bid = blockIdx.x;
    const float* wsrc[4] = {w2, w3, w6, w12};
    const float* bsrc[4] = {b2, b3, b6, b12};
    const int ksA[4] = {2, 3, 6, 12};
    const int plA[4] = {0, 1, 2, 6};
    if (bid >= 14) {    // x -> bf16
        int e4 = (bid - 14) * 1024 + tid;
        float4 u = ((const float4*)x)[e4];
        uint2 w;
        w.x = pk_bf16(u.x, u.y);
        w.y = pk_bf16(u.z, u.w);
        ((uint2*)xb)[e4] = w;
        return;
    }
    if (bid == 13) {
        if (tid < 256) wgT[tid] = wg[(tid & 15) * CC + (tid >> 4)];
        else if (tid < 272) bgp[tid - 256] = bg[tid - 256];
        else if (tid < 336) { int j = tid - 272; bcat[j] = bsrc[j >> 4][j & 15]; }
        for (int e = tid; e < 4096; e += 1024) {
            float v = wsl[e];
            __bf16 h = (__bf16)v;
            wslh[e] = h;
            wsll[e] = (__bf16)(v - (float)h);
        }
        return;
    }
    if (bid != 0) {    // WTg
        int e = (bid - 1) * 1024 + tid;
        int j = e / 192, kk = e - j * 192;
        int d = kk >> 4, c = kk & 15;
        int br = j >> 4, oc = j & 15;
        int k = d - 6 + plA[br];
        float v = (k >= 0 && k < ksA[br]) ? wsrc[br][oc * (CC * ksA[br]) + c * ksA[br] + k] : 0.0f;
        wtg[e] = (__bf16)v;
        return;
    }
    __shared__ int   h[NN];
    __shared__ int   sc[NN];
    __shared__ int   cur[NN];
    __shared__ float dl[NN];
    h[tid] = 0;
    __syncthreads();
    for (int e = tid; e < EE; e += 1024) atomicAdd(&h[ei[EE + e]], 1);
    __syncthreads();
    int v = h[tid];
    sc[tid] = v;
    __syncthreads();
    for (int d = 1; d < NN; d <<= 1) {
        int add = (tid >= d) ? sc[tid - d] : 0;
        __syncthreads();
        sc[tid] += add;
        __syncthreads();
    }
    int oex = sc[tid] - v;
    float dv = rsqrtf((float)v + 1.0f);
    offg[tid] = oex; cntg[tid] = v; dinvg[tid] = dv;
    cur[tid] = oex; dl[tid] = dv;
    __syncthreads();
    for (int e = tid; e < EE; e += 1024) {
        int r = ei[e], c = ei[EE + e];
        int i = atomicAdd(&cur[c], 1);
        src[i] = r;
        wE[i]  = dl[r] * dl[c];
    }
}

// ---------------- fused main (R16 configuration — best measured: 95.7 us) ----------------
// 4 nodes/block (grid 2048, static XCD swizzle bq = blk&7 -> per-XCD L2 locality,
// FETCH 9MB verified R20). LDS union: xs (pre-sync2) / xh,xl2 (post-sync2).
// tconv: wave = oc-block, 6 weight frags in VGPR, x from LDS, C^T float4 stores.
// gcn: wave = node, gather unroll-4, in-register transform, hi/lo slin MFMA.
// No launch_bounds (R21: forcing VGPR 84->64 spills; natural 84 -> 6 blocks/CU).

__global__ __launch_bounds__(256) void k_main(
    const __bf16* __restrict__ xb, const __bf16* __restrict__ wtg,
    const float* __restrict__ bcat,
    const int* __restrict__ off, const int* __restrict__ cnt,
    const int* __restrict__ src, const float* __restrict__ wE, const float* __restrict__ dinv,
    const float* __restrict__ wgT, const float* __restrict__ bgp,
    const __bf16* __restrict__ wslh, const __bf16* __restrict__ wsll,
    const float* __restrict__ bsl, float* __restrict__ out) {
    // union: [0,14592) xs: node*3648B, 76 rows * 24 elems
    //        [0,18432) xh/xl2: node*4608B (+2304 for lo), 16*72 elems each
    __shared__ __align__(16) char smem[18432];
    int tid = threadIdx.x;
    int wave = tid >> 6, lane = tid & 63;
    int l15 = lane & 15, g = lane >> 4;
    int bq = blockIdx.x & 7, nq = blockIdx.x >> 3;
    int n = nq * 4 + wave;
    const __bf16* xbb = xb + (size_t)bq * NN * (TT * CC);

    // tconv A-frags (weights, oc-rows wave*16+l15) + bias
    bf16x8 afr[6];
#pragma unroll
    for (int s = 0; s < 6; s++) {
        const __bf16* p = wtg + (wave * 16 + l15) * 192 + s * 32 + g * 8;
        afr[s] = __builtin_bit_cast(bf16x8, *(const float4*)p);
    }
    float4 bias = *(const float4*)(bcat + wave * 16 + g * 4);

    {   // stage 4 node tiles into xs
        int t = tid >> 2, c0 = (tid & 3) * 4;
#pragma unroll
        for (int node = 0; node < 4; node++) {
            __bf16* xsn = (__bf16*)(smem + node * 3648);
            uint2 w = *(const uint2*)(xbb + (size_t)(nq * 4 + node) * (TT * CC) + tid * 4);
            *(uint2*)(xsn + (t + 6) * 24 + c0) = w;
            if (t == 0) {
#pragma unroll
                for (int r = 0; r < 6; r++) *(uint2*)(xsn + r * 24 + c0) = w;
            }
            if (t == 63) {
#pragma unroll
                for (int r = 70; r < 76; r++) *(uint2*)(xsn + r * 24 + c0) = w;
            }
        }
    }
    __syncthreads();

    // ---- tconv: wave = oc-block over all 4 nodes (reads xs), float4 stores ----
    for (int node = 0; node < 4; node++) {
        const __bf16* xsn = (const __bf16*)(smem + node * 3648);
        size_t bn = (size_t)bq * NN + nq * 4 + node;
        f32x4 acc[4];
#pragma unroll
        for (int m = 0; m < 4; m++) acc[m] = (f32x4){bias.x, bias.y, bias.z, bias.w};
#pragma unroll
        for (int m = 0; m < 4; m++) {
#pragma unroll
            for (int s = 0; s < 6; s++) {
                const __bf16* p = xsn + (m * 16 + l15 + 2 * s + (g >> 1)) * 24 + (g & 1) * 8;
                bf16x8 b = __builtin_bit_cast(bf16x8, *(const float4*)p);
                acc[m] = __builtin_amdgcn_mfma_f32_16x16x32_bf16(afr[s], b, acc[m], 0, 0, 0);
            }
        }
#pragma unroll
        for (int m = 0; m < 4; m++) {
            float4 o;
            o.x = tanh_fast(acc[m][0]); o.y = tanh_fast(acc[m][1]);
            o.z = tanh_fast(acc[m][2]); o.w = tanh_fast(acc[m][3]);
            *(float4*)(out + (bn * TT + m * 16 + l15) * CHO + wave * 16 + g * 4) = o;
        }
    }

    // ---- gather (wave = node, lane = t), unroll-4: 8 tile loads in flight ----
    float ac[16];
    {
        int o0 = off[n], cn_ = cnt[n];
        float d = dinv[n], d2 = d * d;
        const __bf16* st = xbb + (size_t)n * (TT * CC) + lane * 16;
        float4 s0 = *(const float4*)st;
        float4 s1 = *(const float4*)(st + 8);
        {
            unsigned ux = __float_as_uint(s0.x), uy = __float_as_uint(s0.y);
            unsigned uz = __float_as_uint(s0.z), uw = __float_as_uint(s0.w);
            ac[0] = d2 * bflo(ux); ac[1] = d2 * bfhi(ux);
            ac[2] = d2 * bflo(uy); ac[3] = d2 * bfhi(uy);
            ac[4] = d2 * bflo(uz); ac[5] = d2 * bfhi(uz);
            ac[6] = d2 * bflo(uw); ac[7] = d2 * bfhi(uw);
            ux = __float_as_uint(s1.x); uy = __float_as_uint(s1.y);
            uz = __float_as_uint(s1.z); uw = __float_as_uint(s1.w);
            ac[8]  = d2 * bflo(ux); ac[9]  = d2 * bfhi(ux);
            ac[10] = d2 * bflo(uy); ac[11] = d2 * bfhi(uy);
            ac[12] = d2 * bflo(uz); ac[13] = d2 * bfhi(uz);
            ac[14] = d2 * bflo(uw); ac[15] = d2 * bfhi(uw);
        }
        const int* srcp = src + o0;
        const float* wEp = wE + o0;
        int j = 0;
        for (; j + 4 <= cn_; j += 4) {
            int sA = srcp[j], sB = srcp[j + 1], sC = srcp[j + 2], sD = srcp[j + 3];
            float wA = wEp[j], wB = wEp[j + 1], wC = wEp[j + 2], wD = wEp[j + 3];
            const __bf16* pa = xbb + (size_t)sA * (TT * CC) + lane * 16;
            const __bf16* pb = xbb + (size_t)sB * (TT * CC) + lane * 16;
            const __bf16* pc = xbb + (size_t)sC * (TT * CC) + lane * 16;
            const __bf16* pd = xbb + (size_t)sD * (TT * CC) + lane * 16;
            float4 a0 = *(const float4*)pa, a1 = *(const float4*)(pa + 8);
            float4 b0 = *(const float4*)pb, b1 = *(const float4*)(pb + 8);
            float4 c0 = *(const float4*)pc, c1 = *(const float4*)(pc + 8);
            float4 d0 = *(const float4*)pd, d1 = *(const float4*)(pd + 8);
            acc8(ac, 0, wA, a0); acc8(ac, 8, wA, a1);
            acc8(ac, 0, wB, b0); acc8(ac, 8, wB, b1);
            acc8(ac, 0, wC, c0); acc8(ac, 8, wC, c1);
            acc8(ac, 0, wD, d0); acc8(ac, 8, wD, d1);
        }
        for (; j < cn_; j++) {
            int sA = srcp[j];
            float wA = wEp[j];
            const __bf16* pa = xbb + (size_t)sA * (TT * CC) + lane * 16;
            float4 a0 = *(const float4*)pa, a1 = *(const float4*)(pa + 8);
            acc8(ac, 0, wA, a0); acc8(ac, 8, wA, a1);
        }
    }

    // ---- transform in registers: pv[16] (kept live across sync2) ----
    float pv[16];
#pragma unroll
    for (int o = 0; o < 16; o++) {
        float p = bgp[o];
#pragma unroll
        for (int c = 0; c < 16; c++) p = fmaf(wgT[c * 16 + o], ac[c], p);
        pv[o] = p;
    }
    __syncthreads();   // all xs reads done -> safe to overwrite union with xh/xl2

    {   // write hi/lo xlA^T for wave's node
        __bf16* xhn = (__bf16*)(smem + wave * 4608);
        __bf16* xln = (__bf16*)(smem + wave * 4608 + 2304);
#pragma unroll
        for (int o = 0; o < 16; o++) {
            __bf16 h = (__bf16)pv[o];
            xhn[o * 72 + lane] = h;
            xln[o * 72 + lane] = (__bf16)(pv[o] - (float)h);
        }
    }
    __syncthreads();

    // ---- slin MFMA: wave = s-quadrant, loop 4 nodes ----
    int sglob = wave * 16 + l15;
    bf16x8 bh[2], bl[2];
#pragma unroll
    for (int k = 0; k < 2; k++) {
        bh[k] = __builtin_bit_cast(bf16x8, *(const float4*)(wslh + sglob * 64 + k * 32 + g * 8));
        bl[k] = __builtin_bit_cast(bf16x8, *(const float4*)(wsll + sglob * 64 + k * 32 + g * 8));
    }
    float bv = bsl[sglob];
    for (int node = 0; node < 4; node++) {
        const __bf16* xhn = (const __bf16*)(smem + node * 4608);
        const __bf16* xln = (const __bf16*)(smem + node * 4608 + 2304);
        f32x4 acc = (f32x4){bv, bv, bv, bv};
        bf16x8 ah[2], al[2];
#pragma unroll
        for (int k = 0; k < 2; k++) {
            ah[k] = __builtin_bit_cast(bf16x8, *(const float4*)(xhn + l15 * 72 + k * 32 + g * 8));
            al[k] = __builtin_bit_cast(bf16x8, *(const float4*)(xln + l15 * 72 + k * 32 + g * 8));
        }
#pragma unroll
        for (int k = 0; k < 2; k++) {
            acc = __builtin_amdgcn_mfma_f32_16x16x32_bf16(ah[k], bh[k], acc, 0, 0, 0);
            acc = __builtin_amdgcn_mfma_f32_16x16x32_bf16(al[k], bh[k], acc, 0, 0, 0);
            acc = __builtin_amdgcn_mfma_f32_16x16x32_bf16(ah[k], bl[k], acc, 0, 0, 0);
        }
        float4 o4;
        o4.x = tanh_fast(acc[0]); o4.y = tanh_fast(acc[1]);
        o4.z = tanh_fast(acc[2]); o4.w = tanh_fast(acc[3]);
        size_t bn = (size_t)bq * NN + nq * 4 + node;
        *(float4*)(out + (bn * TT + sglob) * CHO + 64 + g * 4) = o4;
    }
}

// ---------------- launch ----------------

extern "C" void kernel_launch(void* const* d_in, const int* in_sizes, int n_in,
                              void* d_out, int out_size, void* d_ws, size_t ws_size,
                              hipStream_t stream) {
    const float* x   = (const float*)d_in[0];
    const int*   ei  = (const int*)d_in[1];
    const float* w2  = (const float*)d_in[2];
    const float* b2  = (const float*)d_in[3];
    const float* w3  = (const float*)d_in[4];
    const float* b3  = (const float*)d_in[5];
    const float* w6  = (const float*)d_in[6];
    const float* b6  = (const float*)d_in[7];
    const float* w12 = (const float*)d_in[8];
    const float* b12 = (const float*)d_in[9];
    const float* wg  = (const float*)d_in[10];
    const float* bg  = (const float*)d_in[11];
    const float* wsl = (const float*)d_in[12];
    const float* bsl = (const float*)d_in[13];
    float* out = (float*)d_out;

    // ws layout (bytes): off|cnt|dinv|src|wE|wgT|bgp|bcat|wslh|wsll|wtg ... xb @4MB
    char*   ws   = (char*)d_ws;
    int*    off  = (int*)(ws);
    int*    cnt  = (int*)(ws + 4096);
    float*  dinv = (float*)(ws + 8192);
    int*    src  = (int*)(ws + 12288);
    float*  wE   = (float*)(ws + 77824);
    float*  wgT  = (float*)(ws + 143360);
    float*  bgp  = (float*)(ws + 144384);
    float*  bcat = (float*)(ws + 144448);
    __bf16* wslh = (__bf16*)(ws + 144704);
    __bf16* wsll = (__bf16*)(ws + 152896);
    __bf16* wtg  = (__bf16*)(ws + 161088);
    __bf16* xb   = (__bf16*)(ws + 4194304);

    k_prep<<<2062, 1024, 0, stream>>>(ei, x, w2, b2, w3, b3, w6, b6, w12, b12, wg, bg, wsl,
                                      off, cnt, dinv, src, wE, wgT, bgp, bcat,
                                      wslh, wsll, wtg, xb);
    k_main<<<BB * NN / 4, 256, 0, stream>>>(xb, wtg, bcat, off, cnt, src, wE, dinv,
                                            wgT, bgp, wslh, wsll, bsl, out);
}